// Round 1
// 1298.371 us; speedup vs baseline: 1.0459x; 1.0459x over previous
//
#include <hip/hip_runtime.h>
#include <cstdint>
#include <cstddef>
#include <climits>

#define WAVES_PER_BLOCK 4

// Mark segment start offsets from sorted seg_ids.
// seg_start[n] = first index i with seg_ids[i] >= n; seg_start[N] = M.
__global__ __launch_bounds__(256) void seg_bounds_kernel(
    const int* __restrict__ seg_ids, int* __restrict__ seg_start, int M, int N) {
    int i = blockIdx.x * blockDim.x + threadIdx.x;
    if (i >= M) return;
    int cur  = seg_ids[i];
    int prev = (i == 0) ? -1 : seg_ids[i - 1];
    for (int n = prev + 1; n <= cur; ++n) seg_start[n] = i;
    if (i == M - 1) {
        for (int n = cur + 1; n <= N; ++n) seg_start[n] = M;
    }
}

// One wave per segment. Chunked online softmax: 8 rows per chunk.
// Half-wave float4 layout: lanes 0-31 load the even row of a pair (16B each,
// covering dims 4*li..4*li+3), lanes 32-63 the odd row. 4 independent 16B
// loads per chunk + 1-chunk-deep prefetch -> 64B/lane in flight (vs 8B before).
// Score reduce: 5 shfl_xor steps per row-PAIR (both halves reduce their own row
// with the same ops) + 1 cross-half exchange = 24 shuffles per 8 rows (vs 48),
// in 4 independent pipelined chains (vs a serial 6-deep chain per row).
// Online-softmax rescale happens once per chunk instead of once per row.
__global__ __launch_bounds__(256) void seg_softmax_agg_kernel(
    const float4* __restrict__ msgs4,      // [M][32] float4 view of [M,128] f32
    const int*    __restrict__ timestamps, // [M]
    const float4* __restrict__ W4,         // [32] float4 view of [128]
    const float*  __restrict__ b_ptr,      // scalar
    const int*    __restrict__ seg_start,  // [N+1]
    float4*       __restrict__ out_agg4,   // [N][32]
    float*        __restrict__ out_ts,     // [N] (ts as f32, exact < 2^24)
    int N, int M) {
    const int wave = threadIdx.x >> 6;
    const int lane = threadIdx.x & 63;
    const int half = lane >> 5;            // 0 = even row of pair, 1 = odd row
    const int li   = lane & 31;
    const int n = blockIdx.x * WAVES_PER_BLOCK + wave;
    if (n >= N) return;

    const int s = seg_start[n];
    const int e = seg_start[n + 1];

    const float4 w4 = W4[li];
    const float  bb = b_ptr[0];

    // ---- timestamp max: strided over lanes, one butterfly reduce ----
    int tsm = INT_MIN;
    for (int j = s + lane; j < e; j += 64) {
        int tv = timestamps[j];
        tsm = (tv > tsm) ? tv : tsm;
    }
    #pragma unroll
    for (int off = 32; off >= 1; off >>= 1) {
        int o = __shfl_xor(tsm, off);
        tsm = (o > tsm) ? o : tsm;
    }

    float4 acc  = make_float4(0.f, 0.f, 0.f, 0.f);
    float  mrun = -INFINITY;
    float  denom = 0.f;

    if (e > s) {
        // Loads are clamped to M-1 instead of predicated: rows past e get
        // score -inf -> weight exactly 0 -> contribute nothing. No divergent
        // load guards; loads always issue as 4 back-to-back dwordx4.
        float4 nx0, nx1, nx2, nx3;
        nx0 = msgs4[(size_t)min(s + 0 + half, M - 1) * 32 + li];
        nx1 = msgs4[(size_t)min(s + 2 + half, M - 1) * 32 + li];
        nx2 = msgs4[(size_t)min(s + 4 + half, M - 1) * 32 + li];
        nx3 = msgs4[(size_t)min(s + 6 + half, M - 1) * 32 + li];

        for (int j = s; j < e; j += 8) {
            const float4 c0 = nx0, c1 = nx1, c2 = nx2, c3 = nx3;
            const int jn = j + 8;
            if (jn < e) {   // wave-uniform branch: prefetch next chunk
                nx0 = msgs4[(size_t)min(jn + 0 + half, M - 1) * 32 + li];
                nx1 = msgs4[(size_t)min(jn + 2 + half, M - 1) * 32 + li];
                nx2 = msgs4[(size_t)min(jn + 4 + half, M - 1) * 32 + li];
                nx3 = msgs4[(size_t)min(jn + 6 + half, M - 1) * 32 + li];
            }

            // partial dots (4 independent values)
            float p0 = c0.x * w4.x + c0.y * w4.y + c0.z * w4.z + c0.w * w4.w;
            float p1 = c1.x * w4.x + c1.y * w4.y + c1.z * w4.z + c1.w * w4.w;
            float p2 = c2.x * w4.x + c2.y * w4.y + c2.z * w4.z + c2.w * w4.w;
            float p3 = c3.x * w4.x + c3.y * w4.y + c3.z * w4.z + c3.w * w4.w;

            // reduce within each 32-lane half (both rows of each pair at once)
            #pragma unroll
            for (int off = 16; off >= 1; off >>= 1) {
                p0 += __shfl_xor(p0, off);
                p1 += __shfl_xor(p1, off);
                p2 += __shfl_xor(p2, off);
                p3 += __shfl_xor(p3, off);
            }
            // exchange across halves so every lane sees both rows' scores
            const float q0 = __shfl_xor(p0, 32);
            const float q1 = __shfl_xor(p1, 32);
            const float q2 = __shfl_xor(p2, 32);
            const float q3 = __shfl_xor(p3, 32);

            // wave-uniform scores for rows j..j+7; pad rows -> -inf
            const float NEG = -INFINITY;
            const float s0 = (j + 0 < e) ? ((half ? q0 : p0) + bb) : NEG;
            const float s1 = (j + 1 < e) ? ((half ? p0 : q0) + bb) : NEG;
            const float s2 = (j + 2 < e) ? ((half ? q1 : p1) + bb) : NEG;
            const float s3 = (j + 3 < e) ? ((half ? p1 : q1) + bb) : NEG;
            const float s4 = (j + 4 < e) ? ((half ? q2 : p2) + bb) : NEG;
            const float s5 = (j + 5 < e) ? ((half ? p2 : q2) + bb) : NEG;
            const float s6 = (j + 6 < e) ? ((half ? q3 : p3) + bb) : NEG;
            const float s7 = (j + 7 < e) ? ((half ? p3 : q3) + bb) : NEG;

            const float mc = fmaxf(fmaxf(fmaxf(s0, s1), fmaxf(s2, s3)),
                                   fmaxf(fmaxf(s4, s5), fmaxf(s6, s7)));
            const float mnew  = fmaxf(mrun, mc);
            const float alpha = __expf(mrun - mnew);   // first chunk: exp(-inf)=0
            const float w0 = __expf(s0 - mnew);
            const float w1 = __expf(s1 - mnew);
            const float w2 = __expf(s2 - mnew);
            const float w3 = __expf(s3 - mnew);
            const float w4w = __expf(s4 - mnew);
            const float w5 = __expf(s5 - mnew);
            const float w6 = __expf(s6 - mnew);
            const float w7 = __expf(s7 - mnew);

            denom = denom * alpha + (((w0 + w1) + (w2 + w3)) + ((w4w + w5) + (w6 + w7)));

            // weight of the row THIS lane loaded at each step
            const float wl0 = half ? w1 : w0;
            const float wl1 = half ? w3 : w2;
            const float wl2 = half ? w5 : w4w;
            const float wl3 = half ? w7 : w6;

            acc.x = acc.x * alpha + wl0 * c0.x + wl1 * c1.x + wl2 * c2.x + wl3 * c3.x;
            acc.y = acc.y * alpha + wl0 * c0.y + wl1 * c1.y + wl2 * c2.y + wl3 * c3.y;
            acc.z = acc.z * alpha + wl0 * c0.z + wl1 * c1.z + wl2 * c2.z + wl3 * c3.z;
            acc.w = acc.w * alpha + wl0 * c0.w + wl1 * c1.w + wl2 * c2.w + wl3 * c3.w;

            mrun = mnew;
        }
    }

    // combine the two halves' row-partial sums (same dims, different rows)
    acc.x += __shfl_xor(acc.x, 32);
    acc.y += __shfl_xor(acc.y, 32);
    acc.z += __shfl_xor(acc.z, 32);
    acc.w += __shfl_xor(acc.w, 32);

    const float inv = (e > s) ? (1.0f / denom) : 0.0f;
    if (lane < 32) {
        out_agg4[(size_t)n * 32 + lane] =
            make_float4(acc.x * inv, acc.y * inv, acc.z * inv, acc.w * inv);
    }
    if (lane == 0) {
        // segment_max identity for empty int32 segments = INT32_MIN
        out_ts[n] = (e > s) ? (float)tsm : -2147483648.0f;
    }
}

extern "C" void kernel_launch(void* const* d_in, const int* in_sizes, int n_in,
                              void* d_out, int out_size, void* d_ws, size_t ws_size,
                              hipStream_t stream) {
    const float* msgs       = (const float*)d_in[0];
    const int*   seg_ids    = (const int*)d_in[1];
    const int*   timestamps = (const int*)d_in[2];
    const float* W          = (const float*)d_in[3];
    const float* b          = (const float*)d_in[4];

    const int M = in_sizes[1];          // 2,000,000
    const int N = out_size / 129;       // out = N*128 agg + N ts  (D=128)

    int* seg_start = (int*)d_ws;        // (N+1) ints

    float* out_agg = (float*)d_out;
    float* out_ts  = (float*)d_out + (size_t)N * 128;

    seg_bounds_kernel<<<(M + 255) / 256, 256, 0, stream>>>(seg_ids, seg_start, M, N);

    const int blocks = (N + WAVES_PER_BLOCK - 1) / WAVES_PER_BLOCK;
    seg_softmax_agg_kernel<<<blocks, 256, 0, stream>>>(
        (const float4*)msgs, timestamps, (const float4*)W, b, seg_start,
        (float4*)out_agg, out_ts, N, M);
}